// Round 3
// baseline (2536.443 us; speedup 1.0000x reference)
//
#include <hip/hip_runtime.h>
#include <stdint.h>

typedef __attribute__((ext_vector_type(8))) short  short8;
typedef __attribute__((ext_vector_type(4))) float  f32x4;

static constexpr float BETA = 0.95f;

// ---------- bf16 helpers ----------
__device__ __forceinline__ unsigned short f2bf(float f) {
  uint32_t u = __float_as_uint(f);
  uint32_t r = (u + 0x7fffu + ((u >> 16) & 1u)) >> 16;   // RNE
  return (unsigned short)r;
}
__device__ __forceinline__ float bf2f(unsigned short s) {
  return __uint_as_float((uint32_t)s << 16);
}

// ---------- async global->LDS (16B/lane, wave-uniform LDS base) ----------
__device__ __forceinline__ void gload16(const void* g, void* l) {
  __builtin_amdgcn_global_load_lds(
      (const __attribute__((address_space(1))) uint32_t*)g,
      (__attribute__((address_space(3))) uint32_t*)l, 16, 0, 0);
}

// ---------- conversion kernels ----------
__global__ void cvt_x_k(const float* __restrict__ x, unsigned short* __restrict__ xb) {
  int i = blockIdx.x * blockDim.x + threadIdx.x;
  int k8 = i & 127;
  int bt = i >> 7;
  int b = bt / 5, t = bt - b * 5;
  const f32x4* s = (const f32x4*)(x + (size_t)bt * 1024 + (size_t)k8 * 8);
  unsigned short* d = xb + ((size_t)t * 4096 + b) * 1024 + (size_t)k8 * 8;
  f32x4 a = s[0], c = s[1];
  short8 o;
#pragma unroll
  for (int j = 0; j < 4; ++j) { o[j] = (short)f2bf(a[j]); o[4 + j] = (short)f2bf(c[j]); }
  *(short8*)d = o;
}

__global__ void cvt_w_k(const float* __restrict__ src, unsigned short* __restrict__ dst, int n8) {
  int i = blockIdx.x * blockDim.x + threadIdx.x;
  if (i >= n8) return;
  const f32x4* s = (const f32x4*)src + (size_t)i * 2;
  f32x4 a = s[0], c = s[1];
  short8 o;
#pragma unroll
  for (int j = 0; j < 4; ++j) { o[j] = (short)f2bf(a[j]); o[4 + j] = (short)f2bf(c[j]); }
  *(short8*)(dst + (size_t)i * 8) = o;
}

// ============================================================================
// Ring-pipelined 256x256 GEMM (C = A @ W^T + b) + fused LIF.  BK=64, 8 waves
// (2Mx4N), 512 threads.  LDS: ring of 10 half-tile slots (16 KB each, [128
// rows][8 granules of 8 bf16]), 160 KB -> 1 block/CU.  Granule swizzle
// phys_g = g ^ (row&7) applied on staging global source AND ds_read address
// (LDS dest linear; rule 21).  ONE raw s_barrier per K-tile (asm, opaque ->
// no compiler waitcnt drain); interior (24 ds_read_b128 + 64 MFMA) is left
// unbarriered so the compiler's fine-grained lgkmcnt scheduling interleaves
// ds_read with MFMA (m97-verified mechanism).  Counted vmcnt(4) at each tile
// boundary keeps t+2's A-halves (4 loads) in flight across the barrier.
// Tile t reads slots sb..sb+3 and issues t+1.B0/B1, t+2.A0/A1 into sb+6..sb+9
// (always >=2 slots from any concurrent reader -> race-free at <1-tile skew).
// ============================================================================
template <bool FIRST, int LAYER>
__global__ __launch_bounds__(512, 2) void gemm_ring(
    const unsigned short* __restrict__ A, const unsigned short* __restrict__ W,
    const float* __restrict__ bias,
    float* __restrict__ mem, unsigned short* __restrict__ sbuf,
    float* __restrict__ outacc,
    int M, int N, int K, int nbn)
{
  __shared__ __align__(16) unsigned short lds[10 * 8192];   // 160 KiB

  const int tid  = threadIdx.x;
  const int lane = tid & 63;
  const int wid  = tid >> 6;
  const int wr = wid >> 2, wc = wid & 3;

  // XCD-aware swizzle (grid multiple of 8)
  const int nwg = gridDim.x;
  const int cpx = nwg >> 3;
  const int bid = blockIdx.x;
  const int swz = (bid & 7) * cpx + (bid >> 3);
  const int bm = swz / nbn, bn = swz % nbn;
  const int bmr = bm * 256, bnr = bn * 256;

  // ---- compute-side LDS read offsets (elements); verified absmax=0, 0 conflicts ----
  const int l15 = lane & 15, l7 = lane & 7, lk = lane >> 4;
  const int aoff0 = l15 * 64 + ((lk)     ^ l7) * 8;   // ksub 0 (k 0..31)
  const int aoff1 = l15 * 64 + ((4 + lk) ^ l7) * 8;   // ksub 1 (k 32..63)
  const int bhoff = (wc & 1) * 4096;                  // 64 rows into the B-half

  // ---- staging-side constants ----
  const int srs = lane >> 3;               // sub-row 0..7 within 8-row chunk
  const int sgc = (lane & 7) ^ srs;        // logical granule this lane fetches
  const int ldst = wid * 1024;             // LDS elem offset of this wave's chunk

  const unsigned short* gAt = A + (size_t)(bmr + wid * 16 + srs) * K + sgc * 8;
  const unsigned short* gBt = W + (size_t)(bnr + wid * 16 + srs) * K + sgc * 8;
  const size_t rK8   = (size_t)8 * K;
  const size_t rK128 = (size_t)128 * K;

  auto stA = [&](int slot, int hh, int kt) {
    const unsigned short* g = gAt + (size_t)hh * rK128 + (size_t)kt * 64;
    unsigned short* d = &lds[slot * 8192 + ldst];
    gload16(g, d);
    gload16(g + rK8, d + 512);
  };
  auto stB = [&](int slot, int hh, int kt) {
    const unsigned short* g = gBt + (size_t)hh * rK128 + (size_t)kt * 64;
    unsigned short* d = &lds[slot * 8192 + ldst];
    gload16(g, d);
    gload16(g + rK8, d + 512);
  };

  f32x4 acc[8][4];
#pragma unroll
  for (int m = 0; m < 8; ++m)
#pragma unroll
    for (int n = 0; n < 4; ++n) acc[m][n] = (f32x4){0.f, 0.f, 0.f, 0.f};

  const int nkt = K >> 6;

  // ---- prologue: t0 complete (slots 0-3) + t1.A (slots 4,5) ----
  stA(0, 0, 0); stA(1, 1, 0); stB(2, 0, 0); stB(3, 1, 0);
  if (nkt > 1) {
    stA(4, 0, 1); stA(5, 1, 1);
    asm volatile("s_waitcnt vmcnt(4)" ::: "memory");
  } else {
    asm volatile("s_waitcnt vmcnt(0)" ::: "memory");
  }
  asm volatile("s_barrier");
  __builtin_amdgcn_sched_barrier(0);

  int sb = 0;
  for (int t = 0; t < nkt; ++t) {
    int sA = sb + wr;             if (sA >= 10) sA -= 10;
    int sBs = sb + 2 + (wc >> 1); if (sBs >= 10) sBs -= 10;
    const unsigned short* ab = &lds[sA * 8192];
    const unsigned short* bb = &lds[sBs * 8192] + bhoff;
    const bool p1 = (t + 1 < nkt), p2 = (t + 2 < nkt);
    int s6 = sb + 6; if (s6 >= 10) s6 -= 10;
    int s7 = sb + 7; if (s7 >= 10) s7 -= 10;
    int s8 = sb + 8; if (s8 >= 10) s8 -= 10;
    int s9 = sb + 9; if (s9 >= 10) s9 -= 10;

    // prefetches issued at tile top: B gets a full tile of latency cover,
    // A two tiles.  vmcnt tracked per-wave: 8 loads issued per tile.
    if (p1) { stB(s6, 0, t + 1); stB(s7, 1, t + 1); }
    if (p2) { stA(s8, 0, t + 2); stA(s9, 1, t + 2); }

    short8 af[4], bfr[4];

    // ---- ksub 0 ----
#pragma unroll
    for (int m = 0; m < 4; ++m) af[m] = *(const short8*)(ab + m * 1024 + aoff0);
#pragma unroll
    for (int n = 0; n < 4; ++n) bfr[n] = *(const short8*)(bb + n * 1024 + aoff0);
#pragma unroll
    for (int m = 0; m < 4; ++m)
#pragma unroll
      for (int n = 0; n < 4; ++n)
        acc[m][n] = __builtin_amdgcn_mfma_f32_16x16x32_bf16(af[m], bfr[n], acc[m][n], 0, 0, 0);
#pragma unroll
    for (int m = 0; m < 4; ++m) af[m] = *(const short8*)(ab + (4 + m) * 1024 + aoff0);
#pragma unroll
    for (int m = 0; m < 4; ++m)
#pragma unroll
      for (int n = 0; n < 4; ++n)
        acc[4 + m][n] = __builtin_amdgcn_mfma_f32_16x16x32_bf16(af[m], bfr[n], acc[4 + m][n], 0, 0, 0);

    // ---- ksub 1 ----
#pragma unroll
    for (int m = 0; m < 4; ++m) af[m] = *(const short8*)(ab + m * 1024 + aoff1);
#pragma unroll
    for (int n = 0; n < 4; ++n) bfr[n] = *(const short8*)(bb + n * 1024 + aoff1);
#pragma unroll
    for (int m = 0; m < 4; ++m)
#pragma unroll
      for (int n = 0; n < 4; ++n)
        acc[m][n] = __builtin_amdgcn_mfma_f32_16x16x32_bf16(af[m], bfr[n], acc[m][n], 0, 0, 0);
#pragma unroll
    for (int m = 0; m < 4; ++m) af[m] = *(const short8*)(ab + (4 + m) * 1024 + aoff1);
#pragma unroll
    for (int m = 0; m < 4; ++m)
#pragma unroll
      for (int n = 0; n < 4; ++n)
        acc[4 + m][n] = __builtin_amdgcn_mfma_f32_16x16x32_bf16(af[m], bfr[n], acc[4 + m][n], 0, 0, 0);

    // ---- tile boundary: drain t+1's halves, keep t+2.A (4 loads) flying ----
    if (p2)      asm volatile("s_waitcnt vmcnt(4)" ::: "memory");
    else if (p1) asm volatile("s_waitcnt vmcnt(0)" ::: "memory");
    asm volatile("s_barrier");
    __builtin_amdgcn_sched_barrier(0);

    sb += 4; if (sb >= 10) sb -= 10;
  }

  // ---- LIF epilogue.  C/D: col = lane&15, row = (lane>>4)*4 + j ----
  const int crow0 = bmr + wr * 128;
  const int ccol0 = bnr + wc * 64;
  float bcol[4];
#pragma unroll
  for (int n = 0; n < 4; ++n) bcol[n] = bias[ccol0 + n * 16 + l15];
#pragma unroll
  for (int m = 0; m < 8; ++m) {
#pragma unroll
    for (int n = 0; n < 4; ++n) {
      const int col = ccol0 + n * 16 + l15;
#pragma unroll
      for (int j = 0; j < 4; ++j) {
        const int row = crow0 + m * 16 + lk * 4 + j;
        const size_t idx = (size_t)row * N + col;
        const float curv = acc[m][n][j] + bcol[n];
        const float mold = FIRST ? 0.f : mem[idx];
        const float sprv = FIRST ? 0.f : bf2f(sbuf[idx]);
        const float mnew = BETA * mold + curv - sprv;
        mem[idx] = mnew;
        const float s = (mnew - 1.0f) > 0.f ? 1.f : 0.f;
        sbuf[idx] = f2bf(s);
        if (LAYER == 3) outacc[idx] = FIRST ? s : (outacc[idx] + s);
      }
    }
  }
}

// ---------- host ----------
extern "C" void kernel_launch(void* const* d_in, const int* in_sizes, int n_in,
                              void* d_out, int out_size, void* d_ws, size_t ws_size,
                              hipStream_t stream)
{
  const float* x  = (const float*)d_in[0];
  const float* W1 = (const float*)d_in[1];
  const float* b1 = (const float*)d_in[2];
  const float* W2 = (const float*)d_in[3];
  const float* b2 = (const float*)d_in[4];
  const float* W3 = (const float*)d_in[5];
  const float* b3 = (const float*)d_in[6];
  float* out = (float*)d_out;

  char* p = (char*)d_ws;
  auto wsalloc = [&](size_t bytes) { char* r = p; p += (bytes + 255) & ~(size_t)255; return r; };
  unsigned short* xb   = (unsigned short*)wsalloc((size_t)5 * 4096 * 1024 * 2);
  unsigned short* W1b  = (unsigned short*)wsalloc((size_t)4096 * 1024 * 2);
  unsigned short* W2b  = (unsigned short*)wsalloc((size_t)4096 * 4096 * 2);
  unsigned short* W3b  = (unsigned short*)wsalloc((size_t)1024 * 4096 * 2);
  unsigned short* s1   = (unsigned short*)wsalloc((size_t)4096 * 4096 * 2);
  unsigned short* s2   = (unsigned short*)wsalloc((size_t)4096 * 4096 * 2);
  unsigned short* s3   = (unsigned short*)wsalloc((size_t)4096 * 1024 * 2);
  float* mem1 = (float*)wsalloc((size_t)4096 * 4096 * 4);
  float* mem2 = (float*)wsalloc((size_t)4096 * 4096 * 4);
  float* mem3 = (float*)wsalloc((size_t)4096 * 1024 * 4);

  cvt_x_k<<<dim3(4096 * 5 * 128 / 256), dim3(256), 0, stream>>>(x, xb);
  cvt_w_k<<<dim3(4096 * 1024 / 8 / 256), dim3(256), 0, stream>>>(W1, W1b, 4096 * 1024 / 8);
  cvt_w_k<<<dim3(4096 * 4096 / 8 / 256), dim3(256), 0, stream>>>(W2, W2b, 4096 * 4096 / 8);
  cvt_w_k<<<dim3(1024 * 4096 / 8 / 256), dim3(256), 0, stream>>>(W3, W3b, 1024 * 4096 / 8);

  const dim3 blk(512);
  const dim3 g12(256);      // 16x16 tiles of 256  (nbn=16)
  const dim3 g3(64);        // 16x4 tiles          (nbn=4)

  gemm_ring<true, 1><<<g12, blk, 0, stream>>>(xb, W1b, b1, mem1, s1, nullptr, 4096, 4096, 1024, 16);
  gemm_ring<true, 2><<<g12, blk, 0, stream>>>(s1, W2b, b2, mem2, s2, nullptr, 4096, 4096, 4096, 16);
  gemm_ring<true, 3><<<g3,  blk, 0, stream>>>(s2, W3b, b3, mem3, s3, out,     4096, 1024, 4096, 4);
  for (int t = 1; t < 5; ++t) {
    gemm_ring<false, 1><<<g12, blk, 0, stream>>>(xb + (size_t)t * 4096 * 1024, W1b, b1, mem1, s1, nullptr, 4096, 4096, 1024, 16);
    gemm_ring<false, 2><<<g12, blk, 0, stream>>>(s1, W2b, b2, mem2, s2, nullptr, 4096, 4096, 4096, 16);
    gemm_ring<false, 3><<<g3,  blk, 0, stream>>>(s2, W3b, b3, mem3, s3, out,    4096, 1024, 4096, 4);
  }
}

// Round 5
// 1769.527 us; speedup vs baseline: 1.4334x; 1.4334x over previous
//
#include <hip/hip_runtime.h>
#include <stdint.h>

typedef __attribute__((ext_vector_type(8))) short  short8;
typedef __attribute__((ext_vector_type(4))) float  f32x4;

static constexpr float BETA = 0.95f;
static constexpr unsigned ROWCAP = 64;   // per-row spike-list capacity

// ---------- bf16 helpers ----------
__device__ __forceinline__ unsigned short f2bf(float f) {
  uint32_t u = __float_as_uint(f);
  uint32_t r = (u + 0x7fffu + ((u >> 16) & 1u)) >> 16;   // RNE
  return (unsigned short)r;
}
__device__ __forceinline__ float bf2f(unsigned short s) {
  return __uint_as_float((uint32_t)s << 16);
}

// ---------- async global->LDS (16B/lane, wave-uniform LDS base) ----------
__device__ __forceinline__ void gload16(const void* g, void* l) {
  __builtin_amdgcn_global_load_lds(
      (const __attribute__((address_space(1))) uint32_t*)g,
      (__attribute__((address_space(3))) uint32_t*)l, 16, 0, 0);
}

// ---------- conversion kernels ----------
// x[:, t, :] f32 -> xbt [4096][1024] bf16
__global__ void cvt_xt_k(const float* __restrict__ x, unsigned short* __restrict__ xbt, int t) {
  int i = blockIdx.x * blockDim.x + threadIdx.x;      // 4096*128 threads
  int k8 = i & 127, b = i >> 7;
  const f32x4* s = (const f32x4*)(x + ((size_t)b * 5 + t) * 1024 + (size_t)k8 * 8);
  f32x4 a = s[0], c = s[1];
  short8 o;
#pragma unroll
  for (int j = 0; j < 4; ++j) { o[j] = (short)f2bf(a[j]); o[4 + j] = (short)f2bf(c[j]); }
  *(short8*)(xbt + (size_t)b * 1024 + (size_t)k8 * 8) = o;
}

__global__ void cvt_w_k(const float* __restrict__ src, unsigned short* __restrict__ dst, int n8) {
  int i = blockIdx.x * blockDim.x + threadIdx.x;
  if (i >= n8) return;
  const f32x4* s = (const f32x4*)src + (size_t)i * 2;
  f32x4 a = s[0], c = s[1];
  short8 o;
#pragma unroll
  for (int j = 0; j < 4; ++j) { o[j] = (short)f2bf(a[j]); o[4 + j] = (short)f2bf(c[j]); }
  *(short8*)(dst + (size_t)i * 8) = o;
}

// W3 [1024 o][4096 c] f32  ->  W3T [4096 c][1024 o] bf16 (tiled transpose)
__global__ void cvt_w3t_k(const float* __restrict__ W3, unsigned short* __restrict__ W3T) {
  __shared__ float tile[32][33];
  const int tx = threadIdx.x & 31, ty = threadIdx.x >> 5;   // 32 x 8
  const int bc = blockIdx.x * 32, bo = blockIdx.y * 32;
#pragma unroll
  for (int k = 0; k < 4; ++k)
    tile[ty + 8 * k][tx] = W3[(size_t)(bo + ty + 8 * k) * 4096 + bc + tx];
  __syncthreads();
#pragma unroll
  for (int k = 0; k < 4; ++k)
    W3T[(size_t)(bc + ty + 8 * k) * 1024 + bo + tx] = f2bf(tile[tx][ty + 8 * k]);
}

// zero the per-row spike counters (4096 u32)
__global__ void zr_k(unsigned int* __restrict__ rcnt) {
  rcnt[blockIdx.x * blockDim.x + threadIdx.x] = 0u;
}

// ============================================================================
// Ring-pipelined 256x256 GEMM (C = A @ W^T + b) + fused LIF (layers 1,2).
// LAYER==2 appends spiking columns to the per-row list rcnt/rlist.
// Structure verified rounds 2-3: absmax=0, SQ_LDS_BANK_CONFLICT=0.
// ============================================================================
template <bool FIRST, int LAYER>
__global__ __launch_bounds__(512, 2) void gemm_ring(
    const unsigned short* __restrict__ A, const unsigned short* __restrict__ W,
    const float* __restrict__ bias,
    float* __restrict__ mem, unsigned short* __restrict__ sbuf,
    unsigned int* __restrict__ rcnt, unsigned short* __restrict__ rlist,
    int M, int N, int K, int nbn)
{
  __shared__ __align__(16) unsigned short lds[10 * 8192];   // 160 KiB

  const int tid  = threadIdx.x;
  const int lane = tid & 63;
  const int wid  = tid >> 6;
  const int wr = wid >> 2, wc = wid & 3;

  const int nwg = gridDim.x;
  const int cpx = nwg >> 3;
  const int bid = blockIdx.x;
  const int swz = (bid & 7) * cpx + (bid >> 3);
  const int bm = swz / nbn, bn = swz % nbn;
  const int bmr = bm * 256, bnr = bn * 256;

  const int l15 = lane & 15, l7 = lane & 7, lk = lane >> 4;
  const int aoff0 = l15 * 64 + ((lk)     ^ l7) * 8;
  const int aoff1 = l15 * 64 + ((4 + lk) ^ l7) * 8;
  const int bhoff = (wc & 1) * 4096;

  const int srs = lane >> 3;
  const int sgc = (lane & 7) ^ srs;
  const int ldst = wid * 1024;

  const unsigned short* gAt = A + (size_t)(bmr + wid * 16 + srs) * K + sgc * 8;
  const unsigned short* gBt = W + (size_t)(bnr + wid * 16 + srs) * K + sgc * 8;
  const size_t rK8   = (size_t)8 * K;
  const size_t rK128 = (size_t)128 * K;

  auto stA = [&](int slot, int hh, int kt) {
    const unsigned short* g = gAt + (size_t)hh * rK128 + (size_t)kt * 64;
    unsigned short* d = &lds[slot * 8192 + ldst];
    gload16(g, d);
    gload16(g + rK8, d + 512);
  };
  auto stB = [&](int slot, int hh, int kt) {
    const unsigned short* g = gBt + (size_t)hh * rK128 + (size_t)kt * 64;
    unsigned short* d = &lds[slot * 8192 + ldst];
    gload16(g, d);
    gload16(g + rK8, d + 512);
  };

  f32x4 acc[8][4];
#pragma unroll
  for (int m = 0; m < 8; ++m)
#pragma unroll
    for (int n = 0; n < 4; ++n) acc[m][n] = (f32x4){0.f, 0.f, 0.f, 0.f};

  const int nkt = K >> 6;

  stA(0, 0, 0); stA(1, 1, 0); stB(2, 0, 0); stB(3, 1, 0);
  if (nkt > 1) {
    stA(4, 0, 1); stA(5, 1, 1);
    asm volatile("s_waitcnt vmcnt(4)" ::: "memory");
  } else {
    asm volatile("s_waitcnt vmcnt(0)" ::: "memory");
  }
  asm volatile("s_barrier");
  __builtin_amdgcn_sched_barrier(0);

  int sb = 0;
  for (int t = 0; t < nkt; ++t) {
    int sA = sb + wr;             if (sA >= 10) sA -= 10;
    int sBs = sb + 2 + (wc >> 1); if (sBs >= 10) sBs -= 10;
    const unsigned short* ab = &lds[sA * 8192];
    const unsigned short* bb = &lds[sBs * 8192] + bhoff;
    const bool p1 = (t + 1 < nkt), p2 = (t + 2 < nkt);
    int s6 = sb + 6; if (s6 >= 10) s6 -= 10;
    int s7 = sb + 7; if (s7 >= 10) s7 -= 10;
    int s8 = sb + 8; if (s8 >= 10) s8 -= 10;
    int s9 = sb + 9; if (s9 >= 10) s9 -= 10;

    if (p1) { stB(s6, 0, t + 1); stB(s7, 1, t + 1); }
    if (p2) { stA(s8, 0, t + 2); stA(s9, 1, t + 2); }

    short8 af[4], bfr[4];

    // ---- ksub 0 ----
#pragma unroll
    for (int m = 0; m < 4; ++m) af[m] = *(const short8*)(ab + m * 1024 + aoff0);
#pragma unroll
    for (int n = 0; n < 4; ++n) bfr[n] = *(const short8*)(bb + n * 1024 + aoff0);
    __builtin_amdgcn_s_setprio(1);
#pragma unroll
    for (int m = 0; m < 4; ++m)
#pragma unroll
      for (int n = 0; n < 4; ++n)
        acc[m][n] = __builtin_amdgcn_mfma_f32_16x16x32_bf16(af[m], bfr[n], acc[m][n], 0, 0, 0);
    __builtin_amdgcn_s_setprio(0);
#pragma unroll
    for (int m = 0; m < 4; ++m) af[m] = *(const short8*)(ab + (4 + m) * 1024 + aoff0);
    __builtin_amdgcn_s_setprio(1);
#pragma unroll
    for (int m = 0; m < 4; ++m)
#pragma unroll
      for (int n = 0; n < 4; ++n)
        acc[4 + m][n] = __builtin_amdgcn_mfma_f32_16x16x32_bf16(af[m], bfr[n], acc[4 + m][n], 0, 0, 0);
    __builtin_amdgcn_s_setprio(0);

    // ---- ksub 1 ----
#pragma unroll
    for (int m = 0; m < 4; ++m) af[m] = *(const short8*)(ab + m * 1024 + aoff1);
#pragma unroll
    for (int n = 0; n < 4; ++n) bfr[n] = *(const short8*)(bb + n * 1024 + aoff1);
    __builtin_amdgcn_s_setprio(1);
#pragma unroll
    for (int m = 0; m < 4; ++m)
#pragma unroll
      for (int n = 0; n < 4; ++n)
        acc[m][n] = __builtin_amdgcn_mfma_f32_16x16x32_bf16(af[m], bfr[n], acc[m][n], 0, 0, 0);
    __builtin_amdgcn_s_setprio(0);
#pragma unroll
    for (int m = 0; m < 4; ++m) af[m] = *(const short8*)(ab + (4 + m) * 1024 + aoff1);
    __builtin_amdgcn_s_setprio(1);
#pragma unroll
    for (int m = 0; m < 4; ++m)
#pragma unroll
      for (int n = 0; n < 4; ++n)
        acc[4 + m][n] = __builtin_amdgcn_mfma_f32_16x16x32_bf16(af[m], bfr[n], acc[4 + m][n], 0, 0, 0);
    __builtin_amdgcn_s_setprio(0);

    if (p2)      asm volatile("s_waitcnt vmcnt(4)" ::: "memory");
    else if (p1) asm volatile("s_waitcnt vmcnt(0)" ::: "memory");
    asm volatile("s_barrier");
    __builtin_amdgcn_sched_barrier(0);

    sb += 4; if (sb >= 10) sb -= 10;
  }

  // ---- LIF epilogue ----
  const int crow0 = bmr + wr * 128;
  const int ccol0 = bnr + wc * 64;
  float bcol[4];
#pragma unroll
  for (int n = 0; n < 4; ++n) bcol[n] = bias[ccol0 + n * 16 + l15];
#pragma unroll
  for (int m = 0; m < 8; ++m) {
#pragma unroll
    for (int n = 0; n < 4; ++n) {
      const int col = ccol0 + n * 16 + l15;
#pragma unroll
      for (int j = 0; j < 4; ++j) {
        const int row = crow0 + m * 16 + lk * 4 + j;
        const size_t idx = (size_t)row * N + col;
        const float curv = acc[m][n][j] + bcol[n];
        const float mold = FIRST ? 0.f : mem[idx];
        const float sprv = FIRST ? 0.f : bf2f(sbuf[idx]);
        const float mnew = BETA * mold + curv - sprv;
        mem[idx] = mnew;
        const float s = (mnew - 1.0f) > 0.f ? 1.f : 0.f;
        sbuf[idx] = f2bf(s);
        if (LAYER == 2) {
          if (s != 0.f) {                       // rare on this data
            unsigned int slot = atomicAdd(&rcnt[row], 1u);
            if (slot < ROWCAP) rlist[(size_t)row * ROWCAP + slot] = (unsigned short)col;
          }
        }
      }
    }
  }
}

// ---------- layer-3: per-row sparse accumulate + elementwise LIF ----------
template <bool FIRST>
__global__ void lif3_k(const float* __restrict__ b3,
                       const unsigned int* __restrict__ rcnt,
                       const unsigned short* __restrict__ rlist,
                       const unsigned short* __restrict__ s2,
                       const unsigned short* __restrict__ W3T,
                       float* __restrict__ mem3, unsigned short* __restrict__ s3,
                       float* __restrict__ out) {
  const int i = blockIdx.x * blockDim.x + threadIdx.x;   // 1M threads, 4 outs each
  const int r = i >> 8, o0 = (i & 255) * 4;
  const size_t idx = (size_t)r * 1024 + o0;

  const unsigned int cnt = rcnt[r];
  f32x4 cur = (f32x4){0.f, 0.f, 0.f, 0.f};
  if (cnt <= ROWCAP) {
    for (unsigned int e = 0; e < cnt; ++e) {             // cnt ~ 0 on this data
      const unsigned int c = rlist[(size_t)r * ROWCAP + e];
      const ushort4 wv = *(const ushort4*)(W3T + (size_t)c * 1024 + o0);
      cur[0] += bf2f(wv.x); cur[1] += bf2f(wv.y);
      cur[2] += bf2f(wv.z); cur[3] += bf2f(wv.w);
    }
  } else {
    // dense per-row fallback (correct for any density; never triggers here)
    for (int c = 0; c < 4096; ++c) {
      if (s2[(size_t)r * 4096 + c] != 0) {
        const ushort4 wv = *(const ushort4*)(W3T + (size_t)c * 1024 + o0);
        cur[0] += bf2f(wv.x); cur[1] += bf2f(wv.y);
        cur[2] += bf2f(wv.z); cur[3] += bf2f(wv.w);
      }
    }
  }

  const f32x4 bb = *(const f32x4*)(b3 + o0);
  f32x4 mold, sp, ov;
  if (FIRST) {
    mold = (f32x4){0.f, 0.f, 0.f, 0.f};
    sp   = (f32x4){0.f, 0.f, 0.f, 0.f};
  } else {
    mold = *(const f32x4*)(mem3 + idx);
    const ushort4 spv = *(const ushort4*)(s3 + idx);
    sp = (f32x4){bf2f(spv.x), bf2f(spv.y), bf2f(spv.z), bf2f(spv.w)};
    ov = *(const f32x4*)(out + idx);
  }
  f32x4 mnew, sv;
#pragma unroll
  for (int j = 0; j < 4; ++j) {
    mnew[j] = BETA * mold[j] + (cur[j] + bb[j]) - sp[j];
    sv[j] = (mnew[j] - 1.0f) > 0.f ? 1.f : 0.f;
    ov[j] = FIRST ? sv[j] : ov[j] + sv[j];
  }
  *(f32x4*)(mem3 + idx) = mnew;
  ushort4 so = {f2bf(sv[0]), f2bf(sv[1]), f2bf(sv[2]), f2bf(sv[3])};
  *(ushort4*)(s3 + idx) = so;
  *(f32x4*)(out + idx) = ov;
}

// ---------- host ----------
extern "C" void kernel_launch(void* const* d_in, const int* in_sizes, int n_in,
                              void* d_out, int out_size, void* d_ws, size_t ws_size,
                              hipStream_t stream)
{
  const float* x  = (const float*)d_in[0];
  const float* W1 = (const float*)d_in[1];
  const float* b1 = (const float*)d_in[2];
  const float* W2 = (const float*)d_in[3];
  const float* b2 = (const float*)d_in[4];
  const float* W3 = (const float*)d_in[5];
  const float* b3 = (const float*)d_in[6];
  float* out = (float*)d_out;

  // workspace budget: ~272.5 MiB total (proven-safe < 304 MiB used in round 3)
  char* p = (char*)d_ws;
  auto wsalloc = [&](size_t bytes) { char* r = p; p += (bytes + 255) & ~(size_t)255; return r; };
  unsigned short* xbt  = (unsigned short*)wsalloc((size_t)4096 * 1024 * 2);   //  8 MiB
  unsigned short* W1b  = (unsigned short*)wsalloc((size_t)4096 * 1024 * 2);   //  8 MiB
  unsigned short* W2b  = (unsigned short*)wsalloc((size_t)4096 * 4096 * 2);   // 32 MiB
  unsigned short* W3T  = (unsigned short*)wsalloc((size_t)4096 * 1024 * 2);   //  8 MiB
  unsigned short* s1   = (unsigned short*)wsalloc((size_t)4096 * 4096 * 2);   // 32 MiB
  unsigned short* s2   = (unsigned short*)wsalloc((size_t)4096 * 4096 * 2);   // 32 MiB
  unsigned short* s3   = (unsigned short*)wsalloc((size_t)4096 * 1024 * 2);   //  8 MiB
  float* mem1 = (float*)wsalloc((size_t)4096 * 4096 * 4);                     // 64 MiB
  float* mem2 = (float*)wsalloc((size_t)4096 * 4096 * 4);                     // 64 MiB
  float* mem3 = (float*)wsalloc((size_t)4096 * 1024 * 4);                     // 16 MiB
  unsigned int*   rcnt  = (unsigned int*)wsalloc((size_t)4096 * 4);           // 16 KiB
  unsigned short* rlist = (unsigned short*)wsalloc((size_t)4096 * ROWCAP * 2);// 512 KiB

  cvt_w_k<<<dim3(4096 * 1024 / 8 / 256), dim3(256), 0, stream>>>(W1, W1b, 4096 * 1024 / 8);
  cvt_w_k<<<dim3(4096 * 4096 / 8 / 256), dim3(256), 0, stream>>>(W2, W2b, 4096 * 4096 / 8);
  cvt_w3t_k<<<dim3(128, 32), dim3(256), 0, stream>>>(W3, W3T);

  const dim3 blk(512), blkE(256);
  const dim3 g12(256);        // 16x16 tiles of 256 (nbn=16)
  const dim3 gX(2048), gE(4096), gZ(16);

#define STEP(T, FIRSTV)                                                                         \
  cvt_xt_k<<<gX, blkE, 0, stream>>>(x, xbt, T);                                                 \
  gemm_ring<FIRSTV, 1><<<g12, blk, 0, stream>>>(xbt, W1b, b1, mem1, s1, nullptr, nullptr,       \
                                                4096, 4096, 1024, 16);                          \
  zr_k<<<gZ, blkE, 0, stream>>>(rcnt);                                                          \
  gemm_ring<FIRSTV, 2><<<g12, blk, 0, stream>>>(s1, W2b, b2, mem2, s2, rcnt, rlist,             \
                                                4096, 4096, 4096, 16);                          \
  lif3_k<FIRSTV><<<gE, blkE, 0, stream>>>(b3, rcnt, rlist, s2, W3T, mem3, s3, out)

  STEP(0, true);
  STEP(1, false);
  STEP(2, false);
  STEP(3, false);
  STEP(4, false);
#undef STEP
}

// Round 7
// 1733.073 us; speedup vs baseline: 1.4636x; 1.0210x over previous
//
#include <hip/hip_runtime.h>
#include <stdint.h>

typedef __attribute__((ext_vector_type(8))) short  short8;
typedef __attribute__((ext_vector_type(4))) float  f32x4;

static constexpr float BETA = 0.95f;
static constexpr unsigned ROWCAP = 64;   // per-row spike-list capacity

// ---------- bf16 helpers ----------
__device__ __forceinline__ unsigned short f2bf(float f) {
  uint32_t u = __float_as_uint(f);
  uint32_t r = (u + 0x7fffu + ((u >> 16) & 1u)) >> 16;   // RNE
  return (unsigned short)r;
}
__device__ __forceinline__ float bf2f(unsigned short s) {
  return __uint_as_float((uint32_t)s << 16);
}

// ---------- async global->LDS (16B/lane, wave-uniform LDS base) ----------
__device__ __forceinline__ void gload16(const void* g, void* l) {
  __builtin_amdgcn_global_load_lds(
      (const __attribute__((address_space(1))) uint32_t*)g,
      (__attribute__((address_space(3))) uint32_t*)l, 16, 0, 0);
}

// ---------- conversion kernels ----------
// x[:, t, :] f32 -> xbt [4096][1024] bf16
__global__ void cvt_xt_k(const float* __restrict__ x, unsigned short* __restrict__ xbt, int t) {
  int i = blockIdx.x * blockDim.x + threadIdx.x;      // 4096*128 threads
  int k8 = i & 127, b = i >> 7;
  const f32x4* s = (const f32x4*)(x + ((size_t)b * 5 + t) * 1024 + (size_t)k8 * 8);
  f32x4 a = s[0], c = s[1];
  short8 o;
#pragma unroll
  for (int j = 0; j < 4; ++j) { o[j] = (short)f2bf(a[j]); o[4 + j] = (short)f2bf(c[j]); }
  *(short8*)(xbt + (size_t)b * 1024 + (size_t)k8 * 8) = o;
}

__global__ void cvt_w_k(const float* __restrict__ src, unsigned short* __restrict__ dst, int n8) {
  int i = blockIdx.x * blockDim.x + threadIdx.x;
  if (i >= n8) return;
  const f32x4* s = (const f32x4*)src + (size_t)i * 2;
  f32x4 a = s[0], c = s[1];
  short8 o;
#pragma unroll
  for (int j = 0; j < 4; ++j) { o[j] = (short)f2bf(a[j]); o[4 + j] = (short)f2bf(c[j]); }
  *(short8*)(dst + (size_t)i * 8) = o;
}

// W3 [1024 o][4096 c] f32  ->  W3T [4096 c][1024 o] bf16 (tiled transpose)
__global__ void cvt_w3t_k(const float* __restrict__ W3, unsigned short* __restrict__ W3T) {
  __shared__ float tile[32][33];
  const int tx = threadIdx.x & 31, ty = threadIdx.x >> 5;   // 32 x 8
  const int bc = blockIdx.x * 32, bo = blockIdx.y * 32;
#pragma unroll
  for (int k = 0; k < 4; ++k)
    tile[ty + 8 * k][tx] = W3[(size_t)(bo + ty + 8 * k) * 4096 + bc + tx];
  __syncthreads();
#pragma unroll
  for (int k = 0; k < 4; ++k)
    W3T[(size_t)(bc + ty + 8 * k) * 1024 + bo + tx] = f2bf(tile[tx][ty + 8 * k]);
}

// zero the per-row spike counters (4096 u32)
__global__ void zr_k(unsigned int* __restrict__ rcnt) {
  rcnt[blockIdx.x * blockDim.x + threadIdx.x] = 0u;
}

// ============================================================================
// Ring-pipelined 256x256 GEMM (C = A @ W^T + b) + fused LIF (layers 1,2).
// Interior is software-pipelined at the register level: ALL 24 ds_read_b128
// issue at the tile top, one sched_barrier(0), then all 64 MFMAs.  The
// compiler's counted lgkmcnt(16/12/4/0) lets each MFMA cluster's operands
// complete under the previous clusters' MFMAs (one exposed drain per tile
// instead of four).  Staging ring / swizzle / vmcnt(4) discipline unchanged
// (verified rounds 2-5: absmax=0, SQ_LDS_BANK_CONFLICT=0).
// LAYER==2 appends spiking columns to the per-row list rcnt/rlist.
// ============================================================================
template <bool FIRST, int LAYER>
__global__ __launch_bounds__(512, 2) void gemm_ring(
    const unsigned short* __restrict__ A, const unsigned short* __restrict__ W,
    const float* __restrict__ bias,
    float* __restrict__ mem, unsigned short* __restrict__ sbuf,
    unsigned int* __restrict__ rcnt, unsigned short* __restrict__ rlist,
    int M, int N, int K, int nbn)
{
  __shared__ __align__(16) unsigned short lds[10 * 8192];   // 160 KiB

  const int tid  = threadIdx.x;
  const int lane = tid & 63;
  const int wid  = tid >> 6;
  const int wr = wid >> 2, wc = wid & 3;

  const int nwg = gridDim.x;
  const int cpx = nwg >> 3;
  const int bid = blockIdx.x;
  const int swz = (bid & 7) * cpx + (bid >> 3);
  const int bm = swz / nbn, bn = swz % nbn;
  const int bmr = bm * 256, bnr = bn * 256;

  const int l15 = lane & 15, l7 = lane & 7, lk = lane >> 4;
  const int aoff0 = l15 * 64 + ((lk)     ^ l7) * 8;
  const int aoff1 = l15 * 64 + ((4 + lk) ^ l7) * 8;
  const int bhoff = (wc & 1) * 4096;

  const int srs = lane >> 3;
  const int sgc = (lane & 7) ^ srs;
  const int ldst = wid * 1024;

  const unsigned short* gAt = A + (size_t)(bmr + wid * 16 + srs) * K + sgc * 8;
  const unsigned short* gBt = W + (size_t)(bnr + wid * 16 + srs) * K + sgc * 8;
  const size_t rK8   = (size_t)8 * K;
  const size_t rK128 = (size_t)128 * K;

  auto stA = [&](int slot, int hh, int kt) {
    const unsigned short* g = gAt + (size_t)hh * rK128 + (size_t)kt * 64;
    unsigned short* d = &lds[slot * 8192 + ldst];
    gload16(g, d);
    gload16(g + rK8, d + 512);
  };
  auto stB = [&](int slot, int hh, int kt) {
    const unsigned short* g = gBt + (size_t)hh * rK128 + (size_t)kt * 64;
    unsigned short* d = &lds[slot * 8192 + ldst];
    gload16(g, d);
    gload16(g + rK8, d + 512);
  };

  f32x4 acc[8][4];
#pragma unroll
  for (int m = 0; m < 8; ++m)
#pragma unroll
    for (int n = 0; n < 4; ++n) acc[m][n] = (f32x4){0.f, 0.f, 0.f, 0.f};

  const int nkt = K >> 6;

  stA(0, 0, 0); stA(1, 1, 0); stB(2, 0, 0); stB(3, 1, 0);
  if (nkt > 1) {
    stA(4, 0, 1); stA(5, 1, 1);
    asm volatile("s_waitcnt vmcnt(4)" ::: "memory");
  } else {
    asm volatile("s_waitcnt vmcnt(0)" ::: "memory");
  }
  asm volatile("s_barrier");
  __builtin_amdgcn_sched_barrier(0);

  int sb = 0;
  for (int t = 0; t < nkt; ++t) {
    int sA = sb + wr;             if (sA >= 10) sA -= 10;
    int sBs = sb + 2 + (wc >> 1); if (sBs >= 10) sBs -= 10;
    const unsigned short* ab = &lds[sA * 8192];
    const unsigned short* bb = &lds[sBs * 8192] + bhoff;
    const bool p1 = (t + 1 < nkt), p2 = (t + 2 < nkt);
    int s6 = sb + 6; if (s6 >= 10) s6 -= 10;
    int s7 = sb + 7; if (s7 >= 10) s7 -= 10;
    int s8 = sb + 8; if (s8 >= 10) s8 -= 10;
    int s9 = sb + 9; if (s9 >= 10) s9 -= 10;

    // VMEM prefetches for t+1 / t+2 (independent of this tile's compute)
    if (p1) { stB(s6, 0, t + 1); stB(s7, 1, t + 1); }
    if (p2) { stA(s8, 0, t + 2); stA(s9, 1, t + 2); }

    // ---- front burst: ALL 24 ds_read_b128 for this tile ----
    short8 a0[4], b0[4], a1[4], a2[4], b2[4], a3[4];
#pragma unroll
    for (int m = 0; m < 4; ++m) a0[m] = *(const short8*)(ab + m * 1024 + aoff0);
#pragma unroll
    for (int n = 0; n < 4; ++n) b0[n] = *(const short8*)(bb + n * 1024 + aoff0);
#pragma unroll
    for (int m = 0; m < 4; ++m) a1[m] = *(const short8*)(ab + (4 + m) * 1024 + aoff0);
#pragma unroll
    for (int m = 0; m < 4; ++m) a2[m] = *(const short8*)(ab + m * 1024 + aoff1);
#pragma unroll
    for (int n = 0; n < 4; ++n) b2[n] = *(const short8*)(bb + n * 1024 + aoff1);
#pragma unroll
    for (int m = 0; m < 4; ++m) a3[m] = *(const short8*)(ab + (4 + m) * 1024 + aoff1);
    __builtin_amdgcn_sched_barrier(0);   // pin: reads issue before MFMA region

    // ---- MFMA region: compiler inserts counted lgkmcnt(16/12/4/0) ----
#pragma unroll
    for (int m = 0; m < 4; ++m)
#pragma unroll
      for (int n = 0; n < 4; ++n)
        acc[m][n] = __builtin_amdgcn_mfma_f32_16x16x32_bf16(a0[m], b0[n], acc[m][n], 0, 0, 0);
#pragma unroll
    for (int m = 0; m < 4; ++m)
#pragma unroll
      for (int n = 0; n < 4; ++n)
        acc[4 + m][n] = __builtin_amdgcn_mfma_f32_16x16x32_bf16(a1[m], b0[n], acc[4 + m][n], 0, 0, 0);
#pragma unroll
    for (int m = 0; m < 4; ++m)
#pragma unroll
      for (int n = 0; n < 4; ++n)
        acc[m][n] = __builtin_amdgcn_mfma_f32_16x16x32_bf16(a2[m], b2[n], acc[m][n], 0, 0, 0);
#pragma unroll
    for (int m = 0; m < 4; ++m)
#pragma unroll
      for (int n = 0; n < 4; ++n)
        acc[4 + m][n] = __builtin_amdgcn_mfma_f32_16x16x32_bf16(a3[m], b2[n], acc[4 + m][n], 0, 0, 0);

    if (p2)      asm volatile("s_waitcnt vmcnt(4)" ::: "memory");
    else if (p1) asm volatile("s_waitcnt vmcnt(0)" ::: "memory");
    asm volatile("s_barrier");
    __builtin_amdgcn_sched_barrier(0);

    sb += 4; if (sb >= 10) sb -= 10;
  }

  // ---- LIF epilogue ----
  const int crow0 = bmr + wr * 128;
  const int ccol0 = bnr + wc * 64;
  float bcol[4];
#pragma unroll
  for (int n = 0; n < 4; ++n) bcol[n] = bias[ccol0 + n * 16 + l15];
#pragma unroll
  for (int m = 0; m < 8; ++m) {
#pragma unroll
    for (int n = 0; n < 4; ++n) {
      const int col = ccol0 + n * 16 + l15;
#pragma unroll
      for (int j = 0; j < 4; ++j) {
        const int row = crow0 + m * 16 + lk * 4 + j;
        const size_t idx = (size_t)row * N + col;
        const float curv = acc[m][n][j] + bcol[n];
        const float mold = FIRST ? 0.f : mem[idx];
        const float sprv = FIRST ? 0.f : bf2f(sbuf[idx]);
        const float mnew = BETA * mold + curv - sprv;
        mem[idx] = mnew;
        const float s = (mnew - 1.0f) > 0.f ? 1.f : 0.f;
        sbuf[idx] = f2bf(s);
        if (LAYER == 2) {
          if (s != 0.f) {                       // rare on this data
            unsigned int slot = atomicAdd(&rcnt[row], 1u);
            if (slot < ROWCAP) rlist[(size_t)row * ROWCAP + slot] = (unsigned short)col;
          }
        }
      }
    }
  }
}

// ---------- layer-3: per-row sparse accumulate + elementwise LIF ----------
template <bool FIRST>
__global__ void lif3_k(const float* __restrict__ b3,
                       const unsigned int* __restrict__ rcnt,
                       const unsigned short* __restrict__ rlist,
                       const unsigned short* __restrict__ s2,
                       const unsigned short* __restrict__ W3T,
                       float* __restrict__ mem3, unsigned short* __restrict__ s3,
                       float* __restrict__ out) {
  const int i = blockIdx.x * blockDim.x + threadIdx.x;   // 1M threads, 4 outs each
  const int r = i >> 8, o0 = (i & 255) * 4;
  const size_t idx = (size_t)r * 1024 + o0;

  const unsigned int cnt = rcnt[r];
  f32x4 cur = (f32x4){0.f, 0.f, 0.f, 0.f};
  if (cnt <= ROWCAP) {
    for (unsigned int e = 0; e < cnt; ++e) {             // cnt ~ 0 on this data
      const unsigned int c = rlist[(size_t)r * ROWCAP + e];
      const ushort4 wv = *(const ushort4*)(W3T + (size_t)c * 1024 + o0);
      cur[0] += bf2f(wv.x); cur[1] += bf2f(wv.y);
      cur[2] += bf2f(wv.z); cur[3] += bf2f(wv.w);
    }
  } else {
    // dense per-row fallback (correct for any density; never triggers here)
    for (int c = 0; c < 4096; ++c) {
      if (s2[(size_t)r * 4096 + c] != 0) {
        const ushort4 wv = *(const ushort4*)(W3T + (size_t)c * 1024 + o0);
        cur[0] += bf2f(wv.x); cur[1] += bf2f(wv.y);
        cur[2] += bf2f(wv.z); cur[3] += bf2f(wv.w);
      }
    }
  }

  const f32x4 bb = *(const f32x4*)(b3 + o0);
  f32x4 mold, sp, ov;
  if (FIRST) {
    mold = (f32x4){0.f, 0.f, 0.f, 0.f};
    sp   = (f32x4){0.f, 0.f, 0.f, 0.f};
  } else {
    mold = *(const f32x4*)(mem3 + idx);
    const ushort4 spv = *(const ushort4*)(s3 + idx);
    sp = (f32x4){bf2f(spv.x), bf2f(spv.y), bf2f(spv.z), bf2f(spv.w)};
    ov = *(const f32x4*)(out + idx);
  }
  f32x4 mnew, sv;
#pragma unroll
  for (int j = 0; j < 4; ++j) {
    mnew[j] = BETA * mold[j] + (cur[j] + bb[j]) - sp[j];
    sv[j] = (mnew[j] - 1.0f) > 0.f ? 1.f : 0.f;
    ov[j] = FIRST ? sv[j] : ov[j] + sv[j];
  }
  *(f32x4*)(mem3 + idx) = mnew;
  ushort4 so = {f2bf(sv[0]), f2bf(sv[1]), f2bf(sv[2]), f2bf(sv[3])};
  *(ushort4*)(s3 + idx) = so;
  *(f32x4*)(out + idx) = ov;
}

// ---------- host ----------
extern "C" void kernel_launch(void* const* d_in, const int* in_sizes, int n_in,
                              void* d_out, int out_size, void* d_ws, size_t ws_size,
                              hipStream_t stream)
{
  const float* x  = (const float*)d_in[0];
  const float* W1 = (const float*)d_in[1];
  const float* b1 = (const float*)d_in[2];
  const float* W2 = (const float*)d_in[3];
  const float* b2 = (const float*)d_in[4];
  const float* W3 = (const float*)d_in[5];
  const float* b3 = (const float*)d_in[6];
  float* out = (float*)d_out;

  // workspace budget: ~272.5 MiB total (proven-safe < 304 MiB used in round 3)
  char* p = (char*)d_ws;
  auto wsalloc = [&](size_t bytes) { char* r = p; p += (bytes + 255) & ~(size_t)255; return r; };
  unsigned short* xbt  = (unsigned short*)wsalloc((size_t)4096 * 1024 * 2);   //  8 MiB
  unsigned short* W1b  = (unsigned short*)wsalloc((size_t)4096 * 1024 * 2);   //  8 MiB
  unsigned short* W2b  = (unsigned short*)wsalloc((size_t)4096 * 4096 * 2);   // 32 MiB
  unsigned short* W3T  = (unsigned short*)wsalloc((size_t)4096 * 1024 * 2);   //  8 MiB
  unsigned short* s1   = (unsigned short*)wsalloc((size_t)4096 * 4096 * 2);   // 32 MiB
  unsigned short* s2   = (unsigned short*)wsalloc((size_t)4096 * 4096 * 2);   // 32 MiB
  unsigned short* s3   = (unsigned short*)wsalloc((size_t)4096 * 1024 * 2);   //  8 MiB
  float* mem1 = (float*)wsalloc((size_t)4096 * 4096 * 4);                     // 64 MiB
  float* mem2 = (float*)wsalloc((size_t)4096 * 4096 * 4);                     // 64 MiB
  float* mem3 = (float*)wsalloc((size_t)4096 * 1024 * 4);                     // 16 MiB
  unsigned int*   rcnt  = (unsigned int*)wsalloc((size_t)4096 * 4);           // 16 KiB
  unsigned short* rlist = (unsigned short*)wsalloc((size_t)4096 * ROWCAP * 2);// 512 KiB

  cvt_w_k<<<dim3(4096 * 1024 / 8 / 256), dim3(256), 0, stream>>>(W1, W1b, 4096 * 1024 / 8);
  cvt_w_k<<<dim3(4096 * 4096 / 8 / 256), dim3(256), 0, stream>>>(W2, W2b, 4096 * 4096 / 8);
  cvt_w3t_k<<<dim3(128, 32), dim3(256), 0, stream>>>(W3, W3T);

  const dim3 blk(512), blkE(256);
  const dim3 g12(256);        // 16x16 tiles of 256 (nbn=16)
  const dim3 gX(2048), gE(4096), gZ(16);

#define STEP(T, FIRSTV)                                                                         \
  cvt_xt_k<<<gX, blkE, 0, stream>>>(x, xbt, T);                                                 \
  gemm_ring<FIRSTV, 1><<<g12, blk, 0, stream>>>(xbt, W1b, b1, mem1, s1, nullptr, nullptr,       \
                                                4096, 4096, 1024, 16);                          \
  zr_k<<<gZ, blkE, 0, stream>>>(rcnt);                                                          \
  gemm_ring<FIRSTV, 2><<<g12, blk, 0, stream>>>(s1, W2b, b2, mem2, s2, rcnt, rlist,             \
                                                4096, 4096, 4096, 16);                          \
  lif3_k<FIRSTV><<<gE, blkE, 0, stream>>>(b3, rcnt, rlist, s2, W3T, mem3, s3, out)

  STEP(0, true);
  STEP(1, false);
  STEP(2, false);
  STEP(3, false);
  STEP(4, false);
#undef STEP
}

// Round 8
// 1652.866 us; speedup vs baseline: 1.5346x; 1.0485x over previous
//
#include <hip/hip_runtime.h>
#include <stdint.h>

typedef __attribute__((ext_vector_type(8))) short  short8;
typedef __attribute__((ext_vector_type(4))) float  f32x4;

static constexpr float BETA = 0.95f;
static constexpr unsigned ROWCAP = 64;   // per-row spike-list capacity

// ---------- bf16 helpers ----------
__device__ __forceinline__ unsigned short f2bf(float f) {
  uint32_t u = __float_as_uint(f);
  uint32_t r = (u + 0x7fffu + ((u >> 16) & 1u)) >> 16;   // RNE
  return (unsigned short)r;
}
__device__ __forceinline__ float bf2f(unsigned short s) {
  return __uint_as_float((uint32_t)s << 16);
}

// ---------- async global->LDS (16B/lane, wave-uniform LDS base) ----------
__device__ __forceinline__ void gload16(const void* g, void* l) {
  __builtin_amdgcn_global_load_lds(
      (const __attribute__((address_space(1))) uint32_t*)g,
      (__attribute__((address_space(3))) uint32_t*)l, 16, 0, 0);
}

// ---------- conversion kernels ----------
// x[:, t, :] f32 -> xbt [4096][1024] bf16
__global__ void cvt_xt_k(const float* __restrict__ x, unsigned short* __restrict__ xbt, int t) {
  int i = blockIdx.x * blockDim.x + threadIdx.x;      // 4096*128 threads
  int k8 = i & 127, b = i >> 7;
  const f32x4* s = (const f32x4*)(x + ((size_t)b * 5 + t) * 1024 + (size_t)k8 * 8);
  f32x4 a = s[0], c = s[1];
  short8 o;
#pragma unroll
  for (int j = 0; j < 4; ++j) { o[j] = (short)f2bf(a[j]); o[4 + j] = (short)f2bf(c[j]); }
  *(short8*)(xbt + (size_t)b * 1024 + (size_t)k8 * 8) = o;
}

__global__ void cvt_w_k(const float* __restrict__ src, unsigned short* __restrict__ dst, int n8) {
  int i = blockIdx.x * blockDim.x + threadIdx.x;
  if (i >= n8) return;
  const f32x4* s = (const f32x4*)src + (size_t)i * 2;
  f32x4 a = s[0], c = s[1];
  short8 o;
#pragma unroll
  for (int j = 0; j < 4; ++j) { o[j] = (short)f2bf(a[j]); o[4 + j] = (short)f2bf(c[j]); }
  *(short8*)(dst + (size_t)i * 8) = o;
}

// W3 [1024 o][4096 c] f32  ->  W3T [4096 c][1024 o] bf16 (tiled transpose)
__global__ void cvt_w3t_k(const float* __restrict__ W3, unsigned short* __restrict__ W3T) {
  __shared__ float tile[32][33];
  const int tx = threadIdx.x & 31, ty = threadIdx.x >> 5;   // 32 x 8
  const int bc = blockIdx.x * 32, bo = blockIdx.y * 32;
#pragma unroll
  for (int k = 0; k < 4; ++k)
    tile[ty + 8 * k][tx] = W3[(size_t)(bo + ty + 8 * k) * 4096 + bc + tx];
  __syncthreads();
#pragma unroll
  for (int k = 0; k < 4; ++k)
    W3T[(size_t)(bc + ty + 8 * k) * 1024 + bo + tx] = f2bf(tile[tx][ty + 8 * k]);
}

// zero the per-row spike counters (4096 u32)
__global__ void zr_k(unsigned int* __restrict__ rcnt) {
  rcnt[blockIdx.x * blockDim.x + threadIdx.x] = 0u;
}

// ============================================================================
// 256x128-tile ring GEMM (C = A @ W^T + b) + fused LIF, 2 blocks/CU.
// BK=32, 8 waves (2Mx4N), per-wave output 128x32 (acc[8][2] = 64 regs).
// LDS: ring of 10 x 8KB slots (80 KB -> 2 blocks/CU, the whole point).
// Slot = [128 rows][4 granules of 8 bf16]; granule swizzle g^=(row&3) on
// staging source AND ds_read (LDS linear; rule 21).  Per K-tile: 3 slots
// (A0,A1,B), 3 staged loads/thread, ring stride 3 mod 10: tile t reads
// sb..sb+2, writes t+1.B->sb+5, t+2.A->sb+6,7 (disjoint; t's own B slot
// sb+2 was covered by t-1's vmcnt).  Steady-state s_waitcnt vmcnt(2);
// every wave waits its OWN vmcnt before the shared barrier (cross-wave
// staging safety, as rounds 2-7).  Counted-vmcnt + raw barrier verified
// absmax=0 across rounds 2-7.
// LAYER==2 appends spiking columns to the per-row list rcnt/rlist.
// ============================================================================
template <bool FIRST, int LAYER>
__global__ __launch_bounds__(512, 4) void gemm_ring(
    const unsigned short* __restrict__ A, const unsigned short* __restrict__ W,
    const float* __restrict__ bias,
    float* __restrict__ mem, unsigned short* __restrict__ sbuf,
    unsigned int* __restrict__ rcnt, unsigned short* __restrict__ rlist,
    int M, int N, int K, int nbn)
{
  __shared__ __align__(16) unsigned short lds[10 * 4096];   // 80 KiB

  const int tid  = threadIdx.x;
  const int lane = tid & 63;
  const int wid  = tid >> 6;
  const int wr = wid >> 2, wc = wid & 3;

  // XCD-aware swizzle (grid multiple of 8: 512 blocks)
  const int nwg = gridDim.x;
  const int cpx = nwg >> 3;
  const int bid = blockIdx.x;
  const int swz = (bid & 7) * cpx + (bid >> 3);
  const int bm = swz / nbn, bn = swz % nbn;
  const int bmr = bm * 256, bnr = bn * 128;

  // ---- compute-side LDS read offset (elements): row l15, granule lk^(l15&3)
  const int l15 = lane & 15, lk = lane >> 4;
  const int aoff = l15 * 32 + ((lk ^ (l15 & 3)) << 3);

  // ---- staging: thread tid covers row tid>>2, phys granule tid&3 (linear);
  //      source holds logical granule (tid&3)^(row&3)
  const int srow = tid >> 2;
  const int lg   = (tid & 3) ^ (srow & 3);

  const unsigned short* gA0 = A + (size_t)(bmr + srow) * K + lg * 8;
  const unsigned short* gB0 = W + (size_t)(bnr + srow) * K + lg * 8;
  const size_t rK128 = (size_t)128 * K;

  auto stA = [&](int slot, int hh, int kt) {
    gload16(gA0 + (size_t)hh * rK128 + (size_t)kt * 32, &lds[slot * 4096 + tid * 8]);
  };
  auto stB = [&](int slot, int kt) {
    gload16(gB0 + (size_t)kt * 32, &lds[slot * 4096 + tid * 8]);
  };

  f32x4 acc[8][2];
#pragma unroll
  for (int m = 0; m < 8; ++m)
#pragma unroll
    for (int n = 0; n < 2; ++n) acc[m][n] = (f32x4){0.f, 0.f, 0.f, 0.f};

  const int nkt = K >> 5;

  // ---- prologue: t0 complete (slots 0,1,2) + t1.A (slots 3,4) ----
  stA(0, 0, 0); stA(1, 1, 0); stB(2, 0);
  if (nkt > 1) {
    stA(3, 0, 1); stA(4, 1, 1);
    asm volatile("s_waitcnt vmcnt(2)" ::: "memory");
  } else {
    asm volatile("s_waitcnt vmcnt(0)" ::: "memory");
  }
  asm volatile("s_barrier");
  __builtin_amdgcn_sched_barrier(0);

  int sb = 0;
  for (int t = 0; t < nkt; ++t) {
    int sA = sb + wr;  if (sA >= 10) sA -= 10;
    int sB = sb + 2;   if (sB >= 10) sB -= 10;
    const unsigned short* ab = &lds[sA * 4096];
    const unsigned short* bb = &lds[sB * 4096] + wc * 1024;   // wc*32 rows
    const bool p1 = (t + 1 < nkt), p2 = (t + 2 < nkt);
    int s5 = sb + 5; if (s5 >= 10) s5 -= 10;
    int s6 = sb + 6; if (s6 >= 10) s6 -= 10;
    int s7 = sb + 7; if (s7 >= 10) s7 -= 10;

    // prefetches: B(t+1) one-tile cover, A(t+2) two-tile cover
    if (p1) stB(s5, t + 1);
    if (p2) { stA(s6, 0, t + 2); stA(s7, 1, t + 2); }

    short8 bfr[2], af[4];
#pragma unroll
    for (int n = 0; n < 2; ++n) bfr[n] = *(const short8*)(bb + n * 512 + aoff);
#pragma unroll
    for (int m = 0; m < 4; ++m) af[m] = *(const short8*)(ab + m * 512 + aoff);
#pragma unroll
    for (int m = 0; m < 4; ++m)
#pragma unroll
      for (int n = 0; n < 2; ++n)
        acc[m][n] = __builtin_amdgcn_mfma_f32_16x16x32_bf16(af[m], bfr[n], acc[m][n], 0, 0, 0);
#pragma unroll
    for (int m = 0; m < 4; ++m) af[m] = *(const short8*)(ab + (4 + m) * 512 + aoff);
#pragma unroll
    for (int m = 0; m < 4; ++m)
#pragma unroll
      for (int n = 0; n < 2; ++n)
        acc[4 + m][n] = __builtin_amdgcn_mfma_f32_16x16x32_bf16(af[m], bfr[n], acc[4 + m][n], 0, 0, 0);

    // tile boundary: drain through B(t+1); keep A(t+2) (2 loads) in flight
    if (p2)      asm volatile("s_waitcnt vmcnt(2)" ::: "memory");
    else if (p1) asm volatile("s_waitcnt vmcnt(0)" ::: "memory");
    asm volatile("s_barrier");
    __builtin_amdgcn_sched_barrier(0);

    sb += 3; if (sb >= 10) sb -= 10;
  }

  // ---- LIF epilogue.  C/D: col = lane&15, row = (lane>>4)*4 + j ----
  const int crow0 = bmr + wr * 128;
  const int ccol0 = bnr + wc * 32;
  float bcol[2];
#pragma unroll
  for (int n = 0; n < 2; ++n) bcol[n] = bias[ccol0 + n * 16 + l15];
#pragma unroll
  for (int m = 0; m < 8; ++m) {
#pragma unroll
    for (int n = 0; n < 2; ++n) {
      const int col = ccol0 + n * 16 + l15;
#pragma unroll
      for (int j = 0; j < 4; ++j) {
        const int row = crow0 + m * 16 + lk * 4 + j;
        const size_t idx = (size_t)row * N + col;
        const float curv = acc[m][n][j] + bcol[n];
        const float mold = FIRST ? 0.f : mem[idx];
        const float sprv = FIRST ? 0.f : bf2f(sbuf[idx]);
        const float mnew = BETA * mold + curv - sprv;
        mem[idx] = mnew;
        const float s = (mnew - 1.0f) > 0.f ? 1.f : 0.f;
        sbuf[idx] = f2bf(s);
        if (LAYER == 2) {
          if (s != 0.f) {                       // rare on this data
            unsigned int slot = atomicAdd(&rcnt[row], 1u);
            if (slot < ROWCAP) rlist[(size_t)row * ROWCAP + slot] = (unsigned short)col;
          }
        }
      }
    }
  }
}

// ---------- layer-3: per-row sparse accumulate + elementwise LIF ----------
template <bool FIRST>
__global__ void lif3_k(const float* __restrict__ b3,
                       const unsigned int* __restrict__ rcnt,
                       const unsigned short* __restrict__ rlist,
                       const unsigned short* __restrict__ s2,
                       const unsigned short* __restrict__ W3T,
                       float* __restrict__ mem3, unsigned short* __restrict__ s3,
                       float* __restrict__ out) {
  const int i = blockIdx.x * blockDim.x + threadIdx.x;   // 1M threads, 4 outs each
  const int r = i >> 8, o0 = (i & 255) * 4;
  const size_t idx = (size_t)r * 1024 + o0;

  const unsigned int cnt = rcnt[r];
  f32x4 cur = (f32x4){0.f, 0.f, 0.f, 0.f};
  if (cnt <= ROWCAP) {
    for (unsigned int e = 0; e < cnt; ++e) {             // cnt ~ 0 on this data
      const unsigned int c = rlist[(size_t)r * ROWCAP + e];
      const ushort4 wv = *(const ushort4*)(W3T + (size_t)c * 1024 + o0);
      cur[0] += bf2f(wv.x); cur[1] += bf2f(wv.y);
      cur[2] += bf2f(wv.z); cur[3] += bf2f(wv.w);
    }
  } else {
    // dense per-row fallback (correct for any density; never triggers here)
    for (int c = 0; c < 4096; ++c) {
      if (s2[(size_t)r * 4096 + c] != 0) {
        const ushort4 wv = *(const ushort4*)(W3T + (size_t)c * 1024 + o0);
        cur[0] += bf2f(wv.x); cur[1] += bf2f(wv.y);
        cur[2] += bf2f(wv.z); cur[3] += bf2f(wv.w);
      }
    }
  }

  const f32x4 bb = *(const f32x4*)(b3 + o0);
  f32x4 mold, sp, ov;
  if (FIRST) {
    mold = (f32x4){0.f, 0.f, 0.f, 0.f};
    sp   = (f32x4){0.f, 0.f, 0.f, 0.f};
  } else {
    mold = *(const f32x4*)(mem3 + idx);
    const ushort4 spv = *(const ushort4*)(s3 + idx);
    sp = (f32x4){bf2f(spv.x), bf2f(spv.y), bf2f(spv.z), bf2f(spv.w)};
    ov = *(const f32x4*)(out + idx);
  }
  f32x4 mnew, sv;
#pragma unroll
  for (int j = 0; j < 4; ++j) {
    mnew[j] = BETA * mold[j] + (cur[j] + bb[j]) - sp[j];
    sv[j] = (mnew[j] - 1.0f) > 0.f ? 1.f : 0.f;
    ov[j] = FIRST ? sv[j] : ov[j] + sv[j];
  }
  *(f32x4*)(mem3 + idx) = mnew;
  ushort4 so = {f2bf(sv[0]), f2bf(sv[1]), f2bf(sv[2]), f2bf(sv[3])};
  *(ushort4*)(s3 + idx) = so;
  *(f32x4*)(out + idx) = ov;
}

// ---------- host ----------
extern "C" void kernel_launch(void* const* d_in, const int* in_sizes, int n_in,
                              void* d_out, int out_size, void* d_ws, size_t ws_size,
                              hipStream_t stream)
{
  const float* x  = (const float*)d_in[0];
  const float* W1 = (const float*)d_in[1];
  const float* b1 = (const float*)d_in[2];
  const float* W2 = (const float*)d_in[3];
  const float* b2 = (const float*)d_in[4];
  const float* W3 = (const float*)d_in[5];
  const float* b3 = (const float*)d_in[6];
  float* out = (float*)d_out;

  // workspace budget: ~272.5 MiB total (proven-safe; round 5/7 passed)
  char* p = (char*)d_ws;
  auto wsalloc = [&](size_t bytes) { char* r = p; p += (bytes + 255) & ~(size_t)255; return r; };
  unsigned short* xbt  = (unsigned short*)wsalloc((size_t)4096 * 1024 * 2);   //  8 MiB
  unsigned short* W1b  = (unsigned short*)wsalloc((size_t)4096 * 1024 * 2);   //  8 MiB
  unsigned short* W2b  = (unsigned short*)wsalloc((size_t)4096 * 4096 * 2);   // 32 MiB
  unsigned short* W3T  = (unsigned short*)wsalloc((size_t)4096 * 1024 * 2);   //  8 MiB
  unsigned short* s1   = (unsigned short*)wsalloc((size_t)4096 * 4096 * 2);   // 32 MiB
  unsigned short* s2   = (unsigned short*)wsalloc((size_t)4096 * 4096 * 2);   // 32 MiB
  unsigned short* s3   = (unsigned short*)wsalloc((size_t)4096 * 1024 * 2);   //  8 MiB
  float* mem1 = (float*)wsalloc((size_t)4096 * 4096 * 4);                     // 64 MiB
  float* mem2 = (float*)wsalloc((size_t)4096 * 4096 * 4);                     // 64 MiB
  float* mem3 = (float*)wsalloc((size_t)4096 * 1024 * 4);                     // 16 MiB
  unsigned int*   rcnt  = (unsigned int*)wsalloc((size_t)4096 * 4);           // 16 KiB
  unsigned short* rlist = (unsigned short*)wsalloc((size_t)4096 * ROWCAP * 2);// 512 KiB

  cvt_w_k<<<dim3(4096 * 1024 / 8 / 256), dim3(256), 0, stream>>>(W1, W1b, 4096 * 1024 / 8);
  cvt_w_k<<<dim3(4096 * 4096 / 8 / 256), dim3(256), 0, stream>>>(W2, W2b, 4096 * 4096 / 8);
  cvt_w3t_k<<<dim3(128, 32), dim3(256), 0, stream>>>(W3, W3T);

  const dim3 blk(512), blkE(256);
  const dim3 g12(512);        // (4096/256) x (4096/128) tiles; nbn=32; 2 blocks/CU
  const dim3 gX(2048), gE(4096), gZ(16);

#define STEP(T, FIRSTV)                                                                         \
  cvt_xt_k<<<gX, blkE, 0, stream>>>(x, xbt, T);                                                 \
  gemm_ring<FIRSTV, 1><<<g12, blk, 0, stream>>>(xbt, W1b, b1, mem1, s1, nullptr, nullptr,       \
                                                4096, 4096, 1024, 32);                          \
  zr_k<<<gZ, blkE, 0, stream>>>(rcnt);                                                          \
  gemm_ring<FIRSTV, 2><<<g12, blk, 0, stream>>>(s1, W2b, b2, mem2, s2, rcnt, rlist,             \
                                                4096, 4096, 4096, 32);                          \
  lif3_k<FIRSTV><<<gE, blkE, 0, stream>>>(b3, rcnt, rlist, s2, W3T, mem3, s3, out)

  STEP(0, true);
  STEP(1, false);
  STEP(2, false);
  STEP(3, false);
  STEP(4, false);
#undef STEP
}